// Round 12
// baseline (190.340 us; speedup 1.0000x reference)
//
#include <hip/hip_runtime.h>
#include <math.h>

#define N_NODES 50000
#define N_EDGES 800000
#define IN_FEATS 128
#define N_HIDDEN 128
#define N_CLASSES 40
#define SEQ_LEN 20
#define VOCAB 32000
#define BUCKET_CAP 64     // P(in_deg >= 64 | Poisson(16)) ~ 1e-18; guarded anyway

#define NPART 196
#define PCAP 4608         // mean 4096, sigma ~64 -> +8 sigma
// egemm_scat: blocks 0-195 src-scatter, 196-391 dst-scatter, 392-891 egemm
#define EGS_BLOCKS 892
#define POOL_BLOCKS 12500
// poolcount: blocks 0-195 = count (hidden under pool), 196.. = pool
#define POOLCOUNT_BLOCKS (NPART + POOL_BLOCKS)   // 12696
#define PREP_BLOCKS 89    // 1 zero + 64 W1p + 24 W2p
#define GEMM2_BLOCKS 782  // 50048 rows / 64

typedef __attribute__((ext_vector_type(8))) short bf16x8;   // 8 bf16 (4 VGPRs)
typedef __attribute__((ext_vector_type(4))) float f32x4;    // MFMA accumulator

#define AS1 __attribute__((address_space(1)))
#define AS3 __attribute__((address_space(3)))

// Direct global->LDS: per-lane global src, LDS dest = uniform base + lane*16.
__device__ __forceinline__ void gld_lds16(const void* g, void* l) {
    __builtin_amdgcn_global_load_lds((const AS1 unsigned int*)g,
                                     (AS3 unsigned int*)l, 16, 0, 0);
}
__device__ __forceinline__ void vm_wait0() {
    asm volatile("s_waitcnt vmcnt(0)" ::: "memory");
}

// bf16 helpers (RNE)
__device__ inline unsigned short f2bf(float x) {
    union { float f; unsigned int u; } v; v.f = x;
    unsigned int r = v.u + 0x7FFF + ((v.u >> 16) & 1);
    return (unsigned short)(r >> 16);
}
__device__ inline float bf2f(unsigned short b) {
    union { float f; unsigned int u; } v; v.u = ((unsigned int)b) << 16;
    return v.f;
}

// ---------------- workspace layout (bytes) ----------------
//   cnt    : 0        uint[50000] (out_deg<<16 | in_deg; written by poolcount)
//   pcnt_s : 200704   uint[196]+pad (zeroed by prep)
//   pcnt_d : 201728   uint[196]+pad (zeroed by prep)
//   routf  : 202752   f32[50000] rsqrt(out_deg) (written by poolcount)
//   bucketu: 403456   ushort[50000*64]  6.4 MB
//   -- overlay zone (dead before spmm1): --
//   pbuf_s : 6803456  uchar[196*4608]   903 KB
//   pbuf_d : 7706624  uint[196*4608]    3.6 MB
//   Ep     : 11319296 ushort[32000*128] 8.2 MB
//   h1     : 6803456  ushort[50000*128] 12.8 MB  (OVERLAYS pbuf_s+pbuf_d+Ep)
//   -- end overlay --
//   G1     : 19603456 ushort[50000*128] 12.8 MB  (UNSCALED pooled E')
//   G2     : 32403456 ushort[50000*40]  4.0 MB (packed 80B rows)
//   W1p    : 36403456 ushort[128*128]   32 KB
//   W2p    : 36436224 ushort[12*512]    12 KB

// ===== prep: zero both pcnt arrays ∥ pack W1 ∥ pack W2 (MFMA B-frag).
__global__ __launch_bounds__(256) void prep_kernel(
        int4* __restrict__ pcnt_zero, const float* __restrict__ W1,
        unsigned short* __restrict__ W1p, const float* __restrict__ W2,
        unsigned short* __restrict__ W2p) {
    int b = blockIdx.x;
    int t = threadIdx.x;
    if (b == 0) {
        if (t < 128) pcnt_zero[t] = make_int4(0, 0, 0, 0);  // 2048 B = both pcnts
    } else if (b < 65) {
        int i = (b - 1) * 256 + t;  // exactly 16384
        int tile = i >> 9, rem = i & 511;
        int ln = rem >> 3, j = rem & 7;
        int nt = tile >> 2, kb = tile & 3;
        int k = kb * 32 + ((ln >> 4) << 3) + j;
        int n = nt * 16 + (ln & 15);
        W1p[i] = f2bf(W1[k * 128 + n]);
    } else {
        int i = (b - 65) * 256 + t;  // exactly 6144
        int tile = i >> 9, rem = i & 511;
        int ln = rem >> 3, j = rem & 7;
        int nt = tile >> 2, kb = tile & 3;      // nt 0..2
        int k = kb * 32 + ((ln >> 4) << 3) + j;
        int n = nt * 16 + (ln & 15);            // 0..47
        W2p[i] = (n < N_CLASSES) ? f2bf(W2[k * N_CLASSES + n]) : (unsigned short)0;
    }
}

// ===== fused: src-scatter ∥ dst-scatter ∥ egemm (scatter hides under MFMA).
__global__ __launch_bounds__(256) void egemm_scat_kernel(
        const int* __restrict__ src, const int* __restrict__ dst,
        unsigned int* __restrict__ pcnt_s, unsigned char* __restrict__ pbuf_s,
        unsigned int* __restrict__ pcnt_d, unsigned int* __restrict__ pbuf_d,
        const float* __restrict__ emb, const unsigned short* __restrict__ W1p,
        unsigned short* __restrict__ Ep) {
    __shared__ unsigned int shm[512];
    int b = blockIdx.x;
    int t = threadIdx.x;
    if (b < 196) {
        // ---- src scatter: partition src ids by u>>8, 1-byte payload (u&255)
        unsigned int* lhist = shm;
        unsigned int* lbase = shm + 256;
        for (int i = t; i < NPART; i += 256) lhist[i] = 0u;
        __syncthreads();
        int base = b * 4096;
        int pid[16]; unsigned int rank[16]; unsigned char val[16];
        #pragma unroll
        for (int k = 0; k < 16; ++k) {
            int i = base + k * 256 + t;
            pid[k] = -1;
            if (i < N_EDGES) {
                int u = src[i];
                val[k] = (unsigned char)(u & 255);
                pid[k] = u >> 8;
                rank[k] = atomicAdd(&lhist[pid[k]], 1u);
            }
        }
        __syncthreads();
        for (int i = t; i < NPART; i += 256)
            lbase[i] = atomicAdd(&pcnt_s[i], lhist[i]);
        __syncthreads();
        #pragma unroll
        for (int k = 0; k < 16; ++k) {
            if (pid[k] >= 0) {
                unsigned int pos = lbase[pid[k]] + rank[k];
                if (pos < PCAP) pbuf_s[pid[k] * PCAP + pos] = val[k];
            }
        }
    } else if (b < 392) {
        // ---- dst scatter: partition by dst>>8, payload (src<<8)|(dst&255)
        unsigned int* lhist = shm;
        unsigned int* lbase = shm + 256;
        for (int i = t; i < NPART; i += 256) lhist[i] = 0u;
        __syncthreads();
        int base = (b - 196) * 4096;
        int pid[16]; unsigned int rank[16]; unsigned int val[16];
        #pragma unroll
        for (int k = 0; k < 16; ++k) {
            int i = base + k * 256 + t;
            pid[k] = -1;
            if (i < N_EDGES) {
                int u = src[i];
                int d = dst[i];
                val[k] = ((unsigned int)u << 8) | (unsigned int)(d & 255);
                pid[k] = d >> 8;
                rank[k] = atomicAdd(&lhist[pid[k]], 1u);
            }
        }
        __syncthreads();
        for (int i = t; i < NPART; i += 256)
            lbase[i] = atomicAdd(&pcnt_d[i], lhist[i]);
        __syncthreads();
        #pragma unroll
        for (int k = 0; k < 16; ++k) {
            if (pid[k] >= 0) {
                unsigned int pos = lbase[pid[k]] + rank[k];
                if (pos < PCAP) pbuf_d[pid[k] * PCAP + pos] = val[k];
            }
        }
    } else {
        // ---- egemm: E' = emb @ W1 via MFMA (rows (b-392)*64 .. +63)
        const int wave = t >> 6, lane = t & 63;
        const int quad = lane >> 4, m = lane & 15;
        const int row0 = (b - 392) * 64 + wave * 16;
        const int arow = row0 + m;                       // < 32000 always
        const float4* ap = (const float4*)(emb + arow * 128 + quad * 8);
        bf16x8 a[4];
        #pragma unroll
        for (int kb = 0; kb < 4; ++kb) {
            float4 x = ap[kb * 8];
            float4 y = ap[kb * 8 + 1];
            bf16x8 tt;
            tt[0] = f2bf(x.x); tt[1] = f2bf(x.y); tt[2] = f2bf(x.z); tt[3] = f2bf(x.w);
            tt[4] = f2bf(y.x); tt[5] = f2bf(y.y); tt[6] = f2bf(y.z); tt[7] = f2bf(y.w);
            a[kb] = tt;
        }
        const int rbase = row0 + quad * 4;
        #pragma unroll
        for (int nt = 0; nt < 8; ++nt) {
            const unsigned short* wp = W1p + (nt * 4) * 512 + lane * 8;
            bf16x8 b0 = *(const bf16x8*)(wp + 0 * 512);
            bf16x8 b1 = *(const bf16x8*)(wp + 1 * 512);
            bf16x8 b2 = *(const bf16x8*)(wp + 2 * 512);
            bf16x8 b3 = *(const bf16x8*)(wp + 3 * 512);
            f32x4 acc = {0.f, 0.f, 0.f, 0.f};
            acc = __builtin_amdgcn_mfma_f32_16x16x32_bf16(a[0], b0, acc, 0, 0, 0);
            acc = __builtin_amdgcn_mfma_f32_16x16x32_bf16(a[1], b1, acc, 0, 0, 0);
            acc = __builtin_amdgcn_mfma_f32_16x16x32_bf16(a[2], b2, acc, 0, 0, 0);
            acc = __builtin_amdgcn_mfma_f32_16x16x32_bf16(a[3], b3, acc, 0, 0, 0);
            #pragma unroll
            for (int r = 0; r < 4; ++r)
                Ep[(rbase + r) * 128 + nt * 16 + m] = f2bf(acc[r]);
        }
    }
}

// ===== poolcount (R20 form): blocks 0-195 = count; blocks 196.. = pool
// writing UNSCALED G1 = sum/nz (5 size=16 gather instructions per node).
__global__ __launch_bounds__(256) void poolcount_kernel(
        const unsigned int* __restrict__ pcnt_s, const unsigned char* __restrict__ pbuf_s,
        const unsigned int* __restrict__ pcnt_d, const unsigned int* __restrict__ pbuf_d,
        unsigned int* __restrict__ cnt, float* __restrict__ routf,
        unsigned short* __restrict__ bucketu,
        const int* __restrict__ feats, const unsigned short* __restrict__ Ep,
        unsigned short* __restrict__ G1) {
    __shared__ unsigned int shm[4][SEQ_LEN][64];   // 20 KB (count uses 512 uints)
    __shared__ int tokl[4][SEQ_LEN];
    int b = blockIdx.x;
    int t = threadIdx.x;
    if (b < NPART) {
        unsigned int* ho = &shm[0][0][0];
        unsigned int* hi_ = &shm[0][0][0] + 256;
        ho[t] = 0u;
        hi_[t] = 0u;
        __syncthreads();
        int p = b;
        int ns = min((int)pcnt_s[p], PCAP);
        const unsigned char* ps = pbuf_s + p * PCAP;
        for (int i = t; i < ns; i += 256) atomicAdd(&ho[ps[i]], 1u);
        int nd = min((int)pcnt_d[p], PCAP);
        const unsigned int* pd = pbuf_d + p * PCAP;
        for (int i = t; i < nd; i += 256) {
            unsigned int e = pd[i];
            unsigned int d = e & 255u;
            unsigned int slot = atomicAdd(&hi_[d], 1u);
            if (slot < BUCKET_CAP)
                bucketu[(p * 256 + (int)d) * BUCKET_CAP + slot] = (unsigned short)(e >> 8);
        }
        __syncthreads();
        int v = p * 256 + t;
        if (v < N_NODES) {
            cnt[v] = (ho[t] << 16) | (hi_[t] & 0xffffu);
            routf[v] = rsqrtf(fmaxf((float)ho[t], 1.f));
        }
        return;
    }
    // ---- pool role: 4 nodes/block, 5 size=16 gather instructions/node
    int w = t >> 6, lane = t & 63;
    int v = (b - NPART) * 4 + w;
    int mytok = 0;
    if (lane < SEQ_LEN) {
        mytok = feats[v * SEQ_LEN + lane];
        tokl[w][lane] = mytok;
    }
    int nz = (int)__popcll(__ballot(lane < SEQ_LEN && mytok != 0));
    __syncthreads();
    #pragma unroll
    for (int g = 0; g < SEQ_LEN / 4; ++g) {
        int tok = tokl[w][4 * g + (lane >> 4)];
        gld_lds16(Ep + tok * 128 + (lane & 15) * 8, &shm[w][4 * g][0]);
    }
    vm_wait0();
    float a0 = 0.f, a1 = 0.f;
    #pragma unroll
    for (int s = 0; s < SEQ_LEN; ++s) {
        unsigned int x = shm[w][s][lane];
        a0 += bf2f((unsigned short)(x & 0xffffu));
        a1 += bf2f((unsigned short)(x >> 16));
    }
    float sc = 1.f / (float)max(nz, 1);    // UNSCALED (rout applied in spmm1)
    ushort2 o = {f2bf(a0 * sc), f2bf(a1 * sc)};
    ((ushort2*)G1)[v * 64 + lane] = o;
}

// ===== spmm1 (R20 form): gather+aggregate with per-edge rout -> h1.
// 16-row batches, 16.5 KB LDS -> 8 blocks/CU.
__global__ __launch_bounds__(256) void spmm1_kernel(
        const unsigned int* __restrict__ cnt, const float* __restrict__ routf,
        const unsigned short* __restrict__ bucketu, const unsigned short* __restrict__ G,
        const float* __restrict__ b1, unsigned short* __restrict__ h1) {
    __shared__ unsigned short idxs[256];
    __shared__ unsigned int stg[4][16][64];    // 16 KB gather stage
    int t = threadIdx.x;
    int node = t >> 6, lane = t & 63;
    int v = blockIdx.x * 4 + node;
    idxs[t] = bucketu[blockIdx.x * 256 + t];   // wave-local slice
    int ind = (int)(cnt[v] & 0xffffu);
    float rovv = routf[v];
    float2 bb = ((const float2*)b1)[lane];
    int n = min(ind, BUCKET_CAP);
    const unsigned short* bk = &idxs[node * 64];
    float a0 = 0.f, a1 = 0.f;
    for (int base = 0; base < n; base += 16) {
        int m = min(16, n - base);
        int nin = (m + 3) >> 2;
        for (int g = 0; g < nin; ++g) {
            int rc = min(base + 4 * g + (lane >> 4), n - 1);  // clamp partials
            int u = bk[rc];
            gld_lds16(G + u * 128 + (lane & 15) * 8, &stg[node][4 * g][0]);
        }
        float rv[16];
        #pragma unroll
        for (int j = 0; j < 16; ++j)
            rv[j] = routf[bk[base + min(j, m - 1)]];
        vm_wait0();
        #pragma unroll
        for (int j = 0; j < 16; ++j) {
            if (j < m) {
                unsigned int x = stg[node][j][lane];
                a0 += bf2f((unsigned short)(x & 0xffffu)) * rv[j];
                a1 += bf2f((unsigned short)(x >> 16)) * rv[j];
            }
        }
    }
    float rin = rsqrtf(fmaxf((float)ind, 1.f));
    float v0 = fmaxf(a0 * rin + bb.x, 0.f) * rovv;
    float v1 = fmaxf(a1 * rin + bb.y, 0.f) * rovv;
    ushort2 o = {f2bf(v0), f2bf(v1)};
    ((ushort2*)h1)[v * 64 + lane] = o;
}

// ===== gemm2: G2 = h1 @ W2 via MFMA -> PACKED 80B G2 rows (stride 40).
__global__ __launch_bounds__(256) void gemm2_kernel(
        const unsigned short* __restrict__ h1, const unsigned short* __restrict__ W2p,
        unsigned short* __restrict__ G2) {
    const int wave = threadIdx.x >> 6, lane = threadIdx.x & 63;
    const int quad = lane >> 4, m = lane & 15;
    const int row0 = blockIdx.x * 64 + wave * 16;
    const int arow = min(row0 + m, N_NODES - 1);
    const unsigned short* ap = h1 + arow * 128 + quad * 8;
    bf16x8 a0 = *(const bf16x8*)(ap + 0);
    bf16x8 a1 = *(const bf16x8*)(ap + 32);
    bf16x8 a2 = *(const bf16x8*)(ap + 64);
    bf16x8 a3 = *(const bf16x8*)(ap + 96);
    const int rbase = row0 + quad * 4;
    #pragma unroll
    for (int nt = 0; nt < 3; ++nt) {
        const unsigned short* wp = W2p + (nt * 4) * 512 + lane * 8;
        bf16x8 b0 = *(const bf16x8*)(wp + 0 * 512);
        bf16x8 b1 = *(const bf16x8*)(wp + 1 * 512);
        bf16x8 b2 = *(const bf16x8*)(wp + 2 * 512);
        bf16x8 b3 = *(const bf16x8*)(wp + 3 * 512);
        f32x4 acc = {0.f, 0.f, 0.f, 0.f};
        acc = __builtin_amdgcn_mfma_f32_16x16x32_bf16(a0, b0, acc, 0, 0, 0);
        acc = __builtin_amdgcn_mfma_f32_16x16x32_bf16(a1, b1, acc, 0, 0, 0);
        acc = __builtin_amdgcn_mfma_f32_16x16x32_bf16(a2, b2, acc, 0, 0, 0);
        acc = __builtin_amdgcn_mfma_f32_16x16x32_bf16(a3, b3, acc, 0, 0, 0);
        int col = nt * 16 + m;
        #pragma unroll
        for (int r = 0; r < 4; ++r) {
            int row = rbase + r;
            if (row < N_NODES && col < N_CLASSES)
                G2[row * 40 + col] = f2bf(acc[r]);
        }
    }
}

// ===== spmm2: layer-2 aggregate over PACKED 80B G2 rows + epilogue.
// 12 rows per gld instruction (5 lanes x 16B per row; lanes 60-63 -> pad).
__global__ __launch_bounds__(256) void spmm2_kernel(
        const unsigned int* __restrict__ cnt, const unsigned short* __restrict__ bucketu,
        const unsigned short* __restrict__ G2, const float* __restrict__ b2,
        float* __restrict__ out) {
    __shared__ unsigned short idxs[256];
    __shared__ __align__(16) unsigned short stg[4][3][512];  // 12 KB
    int t = threadIdx.x;
    int node = t >> 6, f = t & 63;
    int v = blockIdx.x * 4 + node;
    idxs[t] = bucketu[blockIdx.x * 256 + t];
    int ind = (int)(cnt[v] & 0xffffu);
    int n = min(ind, BUCKET_CAP);
    int jrow = min(f / 5, 11), jsub = f - jrow * 5;   // lanes 60-63 -> row-11 dup
    float acc = 0.f;
    for (int base = 0; base < n; base += 36) {
        int m = min(36, n - base);
        int ng = (m + 11) / 12;
        for (int g = 0; g < ng; ++g) {
            int rc = min(base + 12 * g + jrow, n - 1);
            int u = idxs[node * 64 + rc];
            gld_lds16(G2 + u * 40 + jsub * 8, &stg[node][g][0]);
        }
        vm_wait0();
        if (f < N_CLASSES) {
            for (int g = 0; g < ng; ++g) {
                #pragma unroll
                for (int j = 0; j < 12; ++j) {
                    if (base + 12 * g + j < n)
                        acc += bf2f(stg[node][g][j * 40 + f]);
                }
            }
        }
    }
    if (f < N_CLASSES) {
        float rin = rsqrtf(fmaxf((float)ind, 1.f));
        out[v * N_CLASSES + f] = acc * rin + b2[f];
    }
}

extern "C" void kernel_launch(void* const* d_in, const int* in_sizes, int n_in,
                              void* d_out, int out_size, void* d_ws, size_t ws_size,
                              hipStream_t stream) {
    const int*   feats = (const int*)d_in[0];
    const int*   src   = (const int*)d_in[1];
    const int*   dst   = (const int*)d_in[2];
    const float* emb   = (const float*)d_in[3];
    const float* W1    = (const float*)d_in[4];
    const float* b1    = (const float*)d_in[5];
    const float* W2    = (const float*)d_in[6];
    const float* b2    = (const float*)d_in[7];
    float* out = (float*)d_out;

    char* w = (char*)d_ws;
    unsigned int*   cnt     = (unsigned int*)(w + 0);
    unsigned int*   pcnt_s  = (unsigned int*)(w + 200704);
    unsigned int*   pcnt_d  = (unsigned int*)(w + 201728);
    float*          routf   = (float*)(w + 202752);
    unsigned short* bucketu = (unsigned short*)(w + 403456);
    unsigned char*  pbuf_s  = (unsigned char*)(w + 6803456);
    unsigned int*   pbuf_d  = (unsigned int*)(w + 7706624);
    unsigned short* Ep      = (unsigned short*)(w + 11319296);
    unsigned short* h1      = (unsigned short*)(w + 6803456);   // overlay (dead zone)
    unsigned short* G1      = (unsigned short*)(w + 19603456);
    unsigned short* G2      = (unsigned short*)(w + 32403456);
    unsigned short* W1p     = (unsigned short*)(w + 36403456);
    unsigned short* W2p     = (unsigned short*)(w + 36436224);

    // 1) prep: zero pcnts ∥ pack W1 ∥ pack W2
    prep_kernel<<<PREP_BLOCKS, 256, 0, stream>>>((int4*)pcnt_s, W1, W1p, W2, W2p);
    // 2) src/dst scatter ∥ egemm
    egemm_scat_kernel<<<EGS_BLOCKS, 256, 0, stream>>>(
        src, dst, pcnt_s, pbuf_s, pcnt_d, pbuf_d, emb, W1p, Ep);
    // 3) count (196 blocks, hidden) ∥ pool -> unscaled G1
    poolcount_kernel<<<POOLCOUNT_BLOCKS, 256, 0, stream>>>(
        pcnt_s, pbuf_s, pcnt_d, pbuf_d, cnt, routf, bucketu, feats, Ep, G1);
    // 4) spmm1 (per-edge rout) -> h1
    spmm1_kernel<<<POOL_BLOCKS, 256, 0, stream>>>(cnt, routf, bucketu, G1, b1, h1);
    // 5) G2 = h1 @ W2 via MFMA (packed 80B rows)
    gemm2_kernel<<<GEMM2_BLOCKS, 256, 0, stream>>>(h1, W2p, G2);
    // 6) out = agg(G2)*rin + b2 (packed-row gathers)
    spmm2_kernel<<<POOL_BLOCKS, 256, 0, stream>>>(cnt, bucketu, G2, b2, out);
}

// Round 13
// 185.940 us; speedup vs baseline: 1.0237x; 1.0237x over previous
//
#include <hip/hip_runtime.h>
#include <math.h>

#define N_NODES 50000
#define N_EDGES 800000
#define IN_FEATS 128
#define N_HIDDEN 128
#define N_CLASSES 40
#define SEQ_LEN 20
#define VOCAB 32000
#define BUCKET_CAP 64     // P(in_deg >= 64 | Poisson(16)) ~ 1e-18; guarded anyway

#define NPART 196
#define PCAP 4608         // mean 4096, sigma ~64 -> +8 sigma
// egemm_scat: blocks 0-195 src-scatter, 196-391 dst-scatter, 392-891 egemm
#define EGS_BLOCKS 892
#define POOL_BLOCKS 12500
// poolcount: blocks 0-195 = count (hidden under pool), 196.. = pool
#define POOLCOUNT_BLOCKS (NPART + POOL_BLOCKS)   // 12696
#define PREP_BLOCKS 89    // 1 zero + 64 W1p + 24 W2p
#define GEMM2_BLOCKS 782  // 50048 rows / 64

typedef __attribute__((ext_vector_type(8))) short bf16x8;   // 8 bf16 (4 VGPRs)
typedef __attribute__((ext_vector_type(4))) float f32x4;    // MFMA accumulator

#define AS1 __attribute__((address_space(1)))
#define AS3 __attribute__((address_space(3)))

// Direct global->LDS: per-lane global src, LDS dest = uniform base + lane*16.
// size=16 (dwordx4): one instruction gathers 1KB -> 4x256B rows or 8x128B rows.
__device__ __forceinline__ void gld_lds16(const void* g, void* l) {
    __builtin_amdgcn_global_load_lds((const AS1 unsigned int*)g,
                                     (AS3 unsigned int*)l, 16, 0, 0);
}
__device__ __forceinline__ void vm_wait0() {
    asm volatile("s_waitcnt vmcnt(0)" ::: "memory");
}

// bf16 helpers (RNE)
__device__ inline unsigned short f2bf(float x) {
    union { float f; unsigned int u; } v; v.f = x;
    unsigned int r = v.u + 0x7FFF + ((v.u >> 16) & 1);
    return (unsigned short)(r >> 16);
}
__device__ inline float bf2f(unsigned short b) {
    union { float f; unsigned int u; } v; v.u = ((unsigned int)b) << 16;
    return v.f;
}

// ---------------- workspace layout (bytes) ----------------
//   cnt    : 0        uint[50000] (out_deg<<16 | in_deg; written by poolcount)
//   pcnt_s : 200704   uint[196]+pad (zeroed by prep)
//   pcnt_d : 201728   uint[196]+pad (zeroed by prep)
//   routf  : 202752   f32[50000] rsqrt(out_deg) (written by poolcount)
//   bucketu: 403456   ushort[50000*64]  6.4 MB
//   -- overlay zone (dead before spmm1): --
//   pbuf_s : 6803456  uchar[196*4608]   903 KB
//   pbuf_d : 7706624  uint[196*4608]    3.6 MB
//   Ep     : 11319296 ushort[32000*128] 8.2 MB
//   h1     : 6803456  ushort[50000*128] 12.8 MB  (OVERLAYS pbuf_s+pbuf_d+Ep)
//   -- end overlay --
//   G1     : 19603456 ushort[50000*128] 12.8 MB  (UNSCALED pooled E')
//   G2     : 32403456 ushort[50000*64]  6.4 MB (stride-64, line-aligned rows)
//   W1p    : 38803456 ushort[128*128]   32 KB
//   W2p    : 38836224 ushort[12*512]    12 KB

// ===== prep: zero both pcnt arrays ∥ pack W1 ∥ pack W2 (MFMA B-frag).
__global__ __launch_bounds__(256) void prep_kernel(
        int4* __restrict__ pcnt_zero, const float* __restrict__ W1,
        unsigned short* __restrict__ W1p, const float* __restrict__ W2,
        unsigned short* __restrict__ W2p) {
    int b = blockIdx.x;
    int t = threadIdx.x;
    if (b == 0) {
        if (t < 128) pcnt_zero[t] = make_int4(0, 0, 0, 0);  // 2048 B = both pcnts
    } else if (b < 65) {
        int i = (b - 1) * 256 + t;  // exactly 16384
        int tile = i >> 9, rem = i & 511;
        int ln = rem >> 3, j = rem & 7;
        int nt = tile >> 2, kb = tile & 3;
        int k = kb * 32 + ((ln >> 4) << 3) + j;
        int n = nt * 16 + (ln & 15);
        W1p[i] = f2bf(W1[k * 128 + n]);
    } else {
        int i = (b - 65) * 256 + t;  // exactly 6144
        int tile = i >> 9, rem = i & 511;
        int ln = rem >> 3, j = rem & 7;
        int nt = tile >> 2, kb = tile & 3;      // nt 0..2
        int k = kb * 32 + ((ln >> 4) << 3) + j;
        int n = nt * 16 + (ln & 15);            // 0..47
        W2p[i] = (n < N_CLASSES) ? f2bf(W2[k * N_CLASSES + n]) : (unsigned short)0;
    }
}

// ===== fused: src-scatter ∥ dst-scatter ∥ egemm (scatter hides under MFMA).
__global__ __launch_bounds__(256) void egemm_scat_kernel(
        const int* __restrict__ src, const int* __restrict__ dst,
        unsigned int* __restrict__ pcnt_s, unsigned char* __restrict__ pbuf_s,
        unsigned int* __restrict__ pcnt_d, unsigned int* __restrict__ pbuf_d,
        const float* __restrict__ emb, const unsigned short* __restrict__ W1p,
        unsigned short* __restrict__ Ep) {
    __shared__ unsigned int shm[512];
    int b = blockIdx.x;
    int t = threadIdx.x;
    if (b < 196) {
        // ---- src scatter: partition src ids by u>>8, 1-byte payload (u&255)
        unsigned int* lhist = shm;
        unsigned int* lbase = shm + 256;
        for (int i = t; i < NPART; i += 256) lhist[i] = 0u;
        __syncthreads();
        int base = b * 4096;
        int pid[16]; unsigned int rank[16]; unsigned char val[16];
        #pragma unroll
        for (int k = 0; k < 16; ++k) {
            int i = base + k * 256 + t;
            pid[k] = -1;
            if (i < N_EDGES) {
                int u = src[i];
                val[k] = (unsigned char)(u & 255);
                pid[k] = u >> 8;
                rank[k] = atomicAdd(&lhist[pid[k]], 1u);
            }
        }
        __syncthreads();
        for (int i = t; i < NPART; i += 256)
            lbase[i] = atomicAdd(&pcnt_s[i], lhist[i]);
        __syncthreads();
        #pragma unroll
        for (int k = 0; k < 16; ++k) {
            if (pid[k] >= 0) {
                unsigned int pos = lbase[pid[k]] + rank[k];
                if (pos < PCAP) pbuf_s[pid[k] * PCAP + pos] = val[k];
            }
        }
    } else if (b < 392) {
        // ---- dst scatter: partition by dst>>8, payload (src<<8)|(dst&255)
        unsigned int* lhist = shm;
        unsigned int* lbase = shm + 256;
        for (int i = t; i < NPART; i += 256) lhist[i] = 0u;
        __syncthreads();
        int base = (b - 196) * 4096;
        int pid[16]; unsigned int rank[16]; unsigned int val[16];
        #pragma unroll
        for (int k = 0; k < 16; ++k) {
            int i = base + k * 256 + t;
            pid[k] = -1;
            if (i < N_EDGES) {
                int u = src[i];
                int d = dst[i];
                val[k] = ((unsigned int)u << 8) | (unsigned int)(d & 255);
                pid[k] = d >> 8;
                rank[k] = atomicAdd(&lhist[pid[k]], 1u);
            }
        }
        __syncthreads();
        for (int i = t; i < NPART; i += 256)
            lbase[i] = atomicAdd(&pcnt_d[i], lhist[i]);
        __syncthreads();
        #pragma unroll
        for (int k = 0; k < 16; ++k) {
            if (pid[k] >= 0) {
                unsigned int pos = lbase[pid[k]] + rank[k];
                if (pos < PCAP) pbuf_d[pid[k] * PCAP + pos] = val[k];
            }
        }
    } else {
        // ---- egemm: E' = emb @ W1 via MFMA (rows (b-392)*64 .. +63)
        const int wave = t >> 6, lane = t & 63;
        const int quad = lane >> 4, m = lane & 15;
        const int row0 = (b - 392) * 64 + wave * 16;
        const int arow = row0 + m;                       // < 32000 always
        const float4* ap = (const float4*)(emb + arow * 128 + quad * 8);
        bf16x8 a[4];
        #pragma unroll
        for (int kb = 0; kb < 4; ++kb) {
            float4 x = ap[kb * 8];
            float4 y = ap[kb * 8 + 1];
            bf16x8 tt;
            tt[0] = f2bf(x.x); tt[1] = f2bf(x.y); tt[2] = f2bf(x.z); tt[3] = f2bf(x.w);
            tt[4] = f2bf(y.x); tt[5] = f2bf(y.y); tt[6] = f2bf(y.z); tt[7] = f2bf(y.w);
            a[kb] = tt;
        }
        const int rbase = row0 + quad * 4;
        #pragma unroll
        for (int nt = 0; nt < 8; ++nt) {
            const unsigned short* wp = W1p + (nt * 4) * 512 + lane * 8;
            bf16x8 b0 = *(const bf16x8*)(wp + 0 * 512);
            bf16x8 b1 = *(const bf16x8*)(wp + 1 * 512);
            bf16x8 b2 = *(const bf16x8*)(wp + 2 * 512);
            bf16x8 b3 = *(const bf16x8*)(wp + 3 * 512);
            f32x4 acc = {0.f, 0.f, 0.f, 0.f};
            acc = __builtin_amdgcn_mfma_f32_16x16x32_bf16(a[0], b0, acc, 0, 0, 0);
            acc = __builtin_amdgcn_mfma_f32_16x16x32_bf16(a[1], b1, acc, 0, 0, 0);
            acc = __builtin_amdgcn_mfma_f32_16x16x32_bf16(a[2], b2, acc, 0, 0, 0);
            acc = __builtin_amdgcn_mfma_f32_16x16x32_bf16(a[3], b3, acc, 0, 0, 0);
            #pragma unroll
            for (int r = 0; r < 4; ++r)
                Ep[(rbase + r) * 128 + nt * 16 + m] = f2bf(acc[r]);
        }
    }
}

// ===== poolcount: blocks 0-195 = count (both histograms + buckets,
// LDS-rank, plain stores, zero global atomics); blocks 196.. = pool writing
// UNSCALED G1 = sum/nz (no routf dependency -> count hides under pool).
__global__ __launch_bounds__(256) void poolcount_kernel(
        const unsigned int* __restrict__ pcnt_s, const unsigned char* __restrict__ pbuf_s,
        const unsigned int* __restrict__ pcnt_d, const unsigned int* __restrict__ pbuf_d,
        unsigned int* __restrict__ cnt, float* __restrict__ routf,
        unsigned short* __restrict__ bucketu,
        const int* __restrict__ feats, const unsigned short* __restrict__ Ep,
        unsigned short* __restrict__ G1) {
    __shared__ unsigned int shm[4][SEQ_LEN][64];   // 20 KB (count uses 512 uints)
    __shared__ int tokl[4][SEQ_LEN];
    int b = blockIdx.x;
    int t = threadIdx.x;
    if (b < NPART) {
        // ---- count role (exclusive 256-node ownership per partition)
        unsigned int* ho = &shm[0][0][0];
        unsigned int* hi_ = &shm[0][0][0] + 256;
        ho[t] = 0u;
        hi_[t] = 0u;
        __syncthreads();
        int p = b;
        int ns = min((int)pcnt_s[p], PCAP);
        const unsigned char* ps = pbuf_s + p * PCAP;
        for (int i = t; i < ns; i += 256) atomicAdd(&ho[ps[i]], 1u);
        int nd = min((int)pcnt_d[p], PCAP);
        const unsigned int* pd = pbuf_d + p * PCAP;
        for (int i = t; i < nd; i += 256) {
            unsigned int e = pd[i];
            unsigned int d = e & 255u;
            unsigned int slot = atomicAdd(&hi_[d], 1u);
            if (slot < BUCKET_CAP)
                bucketu[(p * 256 + (int)d) * BUCKET_CAP + slot] = (unsigned short)(e >> 8);
        }
        __syncthreads();
        int v = p * 256 + t;
        if (v < N_NODES) {
            cnt[v] = (ho[t] << 16) | (hi_[t] & 0xffffu);
            routf[v] = rsqrtf(fmaxf((float)ho[t], 1.f));
        }
        return;
    }
    // ---- pool role: 4 nodes/block, 5 size=16 gather instructions/node
    int w = t >> 6, lane = t & 63;
    int v = (b - NPART) * 4 + w;
    int mytok = 0;
    if (lane < SEQ_LEN) {
        mytok = feats[v * SEQ_LEN + lane];
        tokl[w][lane] = mytok;
    }
    int nz = (int)__popcll(__ballot(lane < SEQ_LEN && mytok != 0));
    __syncthreads();
    #pragma unroll
    for (int g = 0; g < SEQ_LEN / 4; ++g) {
        int tok = tokl[w][4 * g + (lane >> 4)];
        gld_lds16(Ep + tok * 128 + (lane & 15) * 8, &shm[w][4 * g][0]);
    }
    vm_wait0();
    float a0 = 0.f, a1 = 0.f;
    #pragma unroll
    for (int s = 0; s < SEQ_LEN; ++s) {
        unsigned int x = shm[w][s][lane];
        a0 += bf2f((unsigned short)(x & 0xffffu));
        a1 += bf2f((unsigned short)(x >> 16));
    }
    float sc = 1.f / (float)max(nz, 1);    // UNSCALED (rout applied in spmm1)
    ushort2 o = {f2bf(a0 * sc), f2bf(a1 * sc)};
    ((ushort2*)G1)[v * 64 + lane] = o;
}

// ===== spmm1: gather+aggregate with per-edge rout -> h1. 16-row batches
// (16.5 KB LDS -> 8 blocks/CU = 32 waves); routf[u] broadcast loads issued
// before the wait (latency-hidden).
__global__ __launch_bounds__(256) void spmm1_kernel(
        const unsigned int* __restrict__ cnt, const float* __restrict__ routf,
        const unsigned short* __restrict__ bucketu, const unsigned short* __restrict__ G,
        const float* __restrict__ b1, unsigned short* __restrict__ h1) {
    __shared__ unsigned short idxs[256];
    __shared__ unsigned int stg[4][16][64];    // 16 KB gather stage
    int t = threadIdx.x;
    int node = t >> 6, lane = t & 63;
    int v = blockIdx.x * 4 + node;
    idxs[t] = bucketu[blockIdx.x * 256 + t];   // wave-local slice
    int ind = (int)(cnt[v] & 0xffffu);
    float rovv = routf[v];
    float2 bb = ((const float2*)b1)[lane];
    int n = min(ind, BUCKET_CAP);
    const unsigned short* bk = &idxs[node * 64];
    float a0 = 0.f, a1 = 0.f;
    for (int base = 0; base < n; base += 16) {
        int m = min(16, n - base);
        int nin = (m + 3) >> 2;
        for (int g = 0; g < nin; ++g) {
            int rc = min(base + 4 * g + (lane >> 4), n - 1);  // clamp partials
            int u = bk[rc];
            gld_lds16(G + u * 128 + (lane & 15) * 8, &stg[node][4 * g][0]);
        }
        // per-edge rout: 16 independent broadcast loads, overlap gld latency
        float rv[16];
        #pragma unroll
        for (int j = 0; j < 16; ++j)
            rv[j] = routf[bk[base + min(j, m - 1)]];
        vm_wait0();
        #pragma unroll
        for (int j = 0; j < 16; ++j) {
            if (j < m) {
                unsigned int x = stg[node][j][lane];
                a0 += bf2f((unsigned short)(x & 0xffffu)) * rv[j];
                a1 += bf2f((unsigned short)(x >> 16)) * rv[j];
            }
        }
    }
    float rin = rsqrtf(fmaxf((float)ind, 1.f));
    float v0 = fmaxf(a0 * rin + bb.x, 0.f) * rovv;
    float v1 = fmaxf(a1 * rin + bb.y, 0.f) * rovv;
    ushort2 o = {f2bf(v0), f2bf(v1)};
    ((ushort2*)h1)[v * 64 + lane] = o;
}

// ===== gemm2: G2 = h1 @ W2 via MFMA (50048x128 @ 128x48, cols>=40 masked).
__global__ __launch_bounds__(256) void gemm2_kernel(
        const unsigned short* __restrict__ h1, const unsigned short* __restrict__ W2p,
        unsigned short* __restrict__ G2) {
    const int wave = threadIdx.x >> 6, lane = threadIdx.x & 63;
    const int quad = lane >> 4, m = lane & 15;
    const int row0 = blockIdx.x * 64 + wave * 16;
    const int arow = min(row0 + m, N_NODES - 1);
    const unsigned short* ap = h1 + arow * 128 + quad * 8;
    bf16x8 a0 = *(const bf16x8*)(ap + 0);
    bf16x8 a1 = *(const bf16x8*)(ap + 32);
    bf16x8 a2 = *(const bf16x8*)(ap + 64);
    bf16x8 a3 = *(const bf16x8*)(ap + 96);
    const int rbase = row0 + quad * 4;
    #pragma unroll
    for (int nt = 0; nt < 3; ++nt) {
        const unsigned short* wp = W2p + (nt * 4) * 512 + lane * 8;
        bf16x8 b0 = *(const bf16x8*)(wp + 0 * 512);
        bf16x8 b1 = *(const bf16x8*)(wp + 1 * 512);
        bf16x8 b2 = *(const bf16x8*)(wp + 2 * 512);
        bf16x8 b3 = *(const bf16x8*)(wp + 3 * 512);
        f32x4 acc = {0.f, 0.f, 0.f, 0.f};
        acc = __builtin_amdgcn_mfma_f32_16x16x32_bf16(a0, b0, acc, 0, 0, 0);
        acc = __builtin_amdgcn_mfma_f32_16x16x32_bf16(a1, b1, acc, 0, 0, 0);
        acc = __builtin_amdgcn_mfma_f32_16x16x32_bf16(a2, b2, acc, 0, 0, 0);
        acc = __builtin_amdgcn_mfma_f32_16x16x32_bf16(a3, b3, acc, 0, 0, 0);
        int col = nt * 16 + m;
        #pragma unroll
        for (int r = 0; r < 4; ++r) {
            int row = rbase + r;
            if (row < N_NODES && col < N_CLASSES)
                G2[row * 64 + col] = f2bf(acc[r]);
        }
    }
}

// ===== spmm2: layer-2 aggregate + epilogue (8 rows per gld instruction;
// 128B line-aligned G2 rows = exactly one line per row).
__global__ __launch_bounds__(256) void spmm2_kernel(
        const unsigned int* __restrict__ cnt, const unsigned short* __restrict__ bucketu,
        const unsigned short* __restrict__ G2, const float* __restrict__ b2,
        float* __restrict__ out) {
    __shared__ unsigned short idxs[256];
    __shared__ unsigned short stg[4][32][64];  // 16 KB; row stride 128B
    int t = threadIdx.x;
    int node = t >> 6, f = t & 63;
    int v = blockIdx.x * 4 + node;
    idxs[t] = bucketu[blockIdx.x * 256 + t];
    int ind = (int)(cnt[v] & 0xffffu);
    int n = min(ind, BUCKET_CAP);
    float acc = 0.f;
    for (int base = 0; base < n; base += 32) {
        int m = min(32, n - base);
        int nin = (m + 7) >> 3;
        for (int g = 0; g < nin; ++g) {
            int rc = min(base + 8 * g + (f >> 3), n - 1);   // clamp partials
            int u = idxs[node * 64 + rc];
            gld_lds16(G2 + u * 64 + (f & 7) * 8, &stg[node][8 * g][0]);
        }
        vm_wait0();
        if (f < N_CLASSES) {
            #pragma unroll 4
            for (int j = 0; j < m; ++j) acc += bf2f(stg[node][j][f]);
        }
    }
    if (f < N_CLASSES) {
        float rin = rsqrtf(fmaxf((float)ind, 1.f));
        out[v * N_CLASSES + f] = acc * rin + b2[f];
    }
}

extern "C" void kernel_launch(void* const* d_in, const int* in_sizes, int n_in,
                              void* d_out, int out_size, void* d_ws, size_t ws_size,
                              hipStream_t stream) {
    const int*   feats = (const int*)d_in[0];
    const int*   src   = (const int*)d_in[1];
    const int*   dst   = (const int*)d_in[2];
    const float* emb   = (const float*)d_in[3];
    const float* W1    = (const float*)d_in[4];
    const float* b1    = (const float*)d_in[5];
    const float* W2    = (const float*)d_in[6];
    const float* b2    = (const float*)d_in[7];
    float* out = (float*)d_out;

    char* w = (char*)d_ws;
    unsigned int*   cnt     = (unsigned int*)(w + 0);
    unsigned int*   pcnt_s  = (unsigned int*)(w + 200704);
    unsigned int*   pcnt_d  = (unsigned int*)(w + 201728);
    float*          routf   = (float*)(w + 202752);
    unsigned short* bucketu = (unsigned short*)(w + 403456);
    unsigned char*  pbuf_s  = (unsigned char*)(w + 6803456);
    unsigned int*   pbuf_d  = (unsigned int*)(w + 7706624);
    unsigned short* Ep      = (unsigned short*)(w + 11319296);
    unsigned short* h1      = (unsigned short*)(w + 6803456);   // overlay (dead zone)
    unsigned short* G1      = (unsigned short*)(w + 19603456);
    unsigned short* G2      = (unsigned short*)(w + 32403456);
    unsigned short* W1p     = (unsigned short*)(w + 38803456);
    unsigned short* W2p     = (unsigned short*)(w + 38836224);

    // 1) prep: zero pcnts ∥ pack W1 ∥ pack W2
    prep_kernel<<<PREP_BLOCKS, 256, 0, stream>>>((int4*)pcnt_s, W1, W1p, W2, W2p);
    // 2) src/dst scatter ∥ egemm
    egemm_scat_kernel<<<EGS_BLOCKS, 256, 0, stream>>>(
        src, dst, pcnt_s, pbuf_s, pcnt_d, pbuf_d, emb, W1p, Ep);
    // 3) count (196 blocks, hidden) ∥ pool -> unscaled G1
    poolcount_kernel<<<POOLCOUNT_BLOCKS, 256, 0, stream>>>(
        pcnt_s, pbuf_s, pcnt_d, pbuf_d, cnt, routf, bucketu, feats, Ep, G1);
    // 4) spmm1 (per-edge rout) -> h1
    spmm1_kernel<<<POOL_BLOCKS, 256, 0, stream>>>(cnt, routf, bucketu, G1, b1, h1);
    // 5) G2 = h1 @ W2 via MFMA
    gemm2_kernel<<<GEMM2_BLOCKS, 256, 0, stream>>>(h1, W2p, G2);
    // 6) out = agg(G2)*rin + b2
    spmm2_kernel<<<POOL_BLOCKS, 256, 0, stream>>>(cnt, bucketu, G2, b2, out);
}